// Round 2
// baseline (4151.479 us; speedup 1.0000x reference)
//
#include <hip/hip_runtime.h>

constexpr int kB  = 4;
constexpr int kT  = 2048;
constexpr int kC  = 1024;
constexpr int kH  = 16;
constexpr int kHS = 64;
constexpr int kFF = 4096;
constexpr int kM  = kB * kT;          // 8192 rows
constexpr int k3C = 3 * kC;           // 3072

// Pack Wq|Wk|Wv [H,C,HS] -> Wqkv [C, 3C] so QKV is one GEMM.
__global__ void repack_qkv(const float* __restrict__ Wq, const float* __restrict__ Wk,
                           const float* __restrict__ Wv, float* __restrict__ Wqkv)
{
    const int idx = blockIdx.x * 256 + threadIdx.x;   // over kC*k3C
    const int j = idx % k3C;
    const int c = idx / k3C;
    const float* src = (j < kC) ? Wq : (j < 2 * kC) ? Wk : Wv;
    const int jj = j & (kC - 1);
    const int h = jj >> 6, d = jj & 63;
    Wqkv[idx] = src[((h << 10) + c) * kHS + d];
}

// C[m,n] = sum_k A[m,k]*B[k,n]  (+bias[n]) (relu?) (+resid[m,n])
// 64x64 tile, BK=16, 256 threads, 4x4 outputs/thread, fp32 throughout.
__global__ __launch_bounds__(256) void gemm_ep(
    const float* __restrict__ A, int lda,
    const float* __restrict__ Bw, int ldb,
    float* __restrict__ Co, int ldc,
    int K,
    const float* __restrict__ bias,
    const float* __restrict__ resid,
    int do_relu)
{
    __shared__ float As[16][68];   // [k][m], pad -> conflict-free
    __shared__ float Bs[16][64];   // [k][n]
    const int tid = threadIdx.x;
    const int m0 = blockIdx.y * 64, n0 = blockIdx.x * 64;
    const int tx = tid & 15, ty = tid >> 4;
    const int la = tid >> 2, lka = (tid & 3) << 2;      // A: row, k-offset
    const int lkb = tid >> 4, lnb = (tid & 15) << 2;    // B: k-row, n-offset
    float acc[4][4] = {{0.f}};
    const float* ap = A + (size_t)(m0 + la) * lda + lka;
    const float* bp = Bw + (size_t)lkb * ldb + n0 + lnb;

    for (int k0 = 0; k0 < K; k0 += 16) {
        float4 av = *(const float4*)(ap + k0);
        float4 bv = *(const float4*)(bp + (size_t)k0 * ldb);
        As[lka + 0][la] = av.x;
        As[lka + 1][la] = av.y;
        As[lka + 2][la] = av.z;
        As[lka + 3][la] = av.w;
        *(float4*)&Bs[lkb][lnb] = bv;
        __syncthreads();
        #pragma unroll
        for (int k = 0; k < 16; ++k) {
            float4 a4 = *(const float4*)&As[k][ty << 2];
            float4 b4 = *(const float4*)&Bs[k][tx << 2];
            float aa[4] = {a4.x, a4.y, a4.z, a4.w};
            float bb[4] = {b4.x, b4.y, b4.z, b4.w};
            #pragma unroll
            for (int i = 0; i < 4; ++i)
                #pragma unroll
                for (int j = 0; j < 4; ++j)
                    acc[i][j] = fmaf(aa[i], bb[j], acc[i][j]);
        }
        __syncthreads();
    }

    #pragma unroll
    for (int i = 0; i < 4; ++i) {
        const int m = m0 + (ty << 2) + i;
        const int n = n0 + (tx << 2);
        float4 v;
        float* vp = (float*)&v;
        #pragma unroll
        for (int j = 0; j < 4; ++j) {
            float t = acc[i][j];
            if (bias)    t += bias[n + j];
            if (do_relu) t = fmaxf(t, 0.f);
            if (resid)   t += resid[(size_t)m * ldc + n + j];
            vp[j] = t;
        }
        *(float4*)(Co + (size_t)m * ldc + n) = v;
    }
}

// Flash-style causal attention. Block = 256 threads: one (b,h,q-tile of 64).
// Thread (qr=tid>>2, dg=tid&3): owns q-row qr, d/s segment dg*16..+15.
// QKV layout: [B*T, 3072]: q at col h*64+d, k at 1024+..., v at 2048+...
__global__ __launch_bounds__(256) void attn_kernel(
    const float* __restrict__ QKV, float* __restrict__ Y)
{
    __shared__ float Kst[64][68];  // transposed: [d][s]
    __shared__ float Vs[64][68];   // [s][d]
    __shared__ float Ps[64][68];   // [q][s]
    const int tid = threadIdx.x;
    const int qt = blockIdx.x, bh = blockIdx.y;
    const int b = bh >> 4, h = bh & 15;
    const int q0 = qt << 6;
    const int qr = tid >> 2, dg = tid & 3;
    const int qg = q0 + qr;
    const float kNegBig = -1e30f;
    const size_t qrow = ((size_t)b * kT + qg) * (size_t)k3C + h * 64;

    float qreg[64];
    #pragma unroll
    for (int i = 0; i < 16; ++i) {
        float4 u = *(const float4*)(QKV + qrow + (i << 2));
        qreg[(i << 2) + 0] = u.x; qreg[(i << 2) + 1] = u.y;
        qreg[(i << 2) + 2] = u.z; qreg[(i << 2) + 3] = u.w;
    }
    float O[16];
    #pragma unroll
    for (int i = 0; i < 16; ++i) O[i] = 0.f;
    float mrun = kNegBig, lrun = 0.f;
    const int ntiles = qt + 1;

    for (int t = 0; t < ntiles; ++t) {
        const int s0 = t << 6;
        __syncthreads();  // protect K/V/P from previous iteration's readers
        {
            const size_t kb = ((size_t)b * kT + s0 + qr) * (size_t)k3C + kC + h * 64 + (dg << 4);
            #pragma unroll
            for (int i = 0; i < 4; ++i) {
                float4 u = *(const float4*)(QKV + kb + (i << 2));
                const int dd = (dg << 4) + (i << 2);
                Kst[dd + 0][qr] = u.x;
                Kst[dd + 1][qr] = u.y;
                Kst[dd + 2][qr] = u.z;
                Kst[dd + 3][qr] = u.w;
                *(float4*)&Vs[qr][dd] = *(const float4*)(QKV + kb + kC + (i << 2));
            }
        }
        __syncthreads();

        float sc[16];
        #pragma unroll
        for (int j = 0; j < 16; ++j) sc[j] = 0.f;
        #pragma unroll
        for (int d = 0; d < 64; ++d) {
            const float qv = qreg[d];
            const float4* kp = (const float4*)&Kst[d][dg << 4];
            float4 k0 = kp[0], k1 = kp[1], k2 = kp[2], k3 = kp[3];
            sc[0]  = fmaf(qv, k0.x, sc[0]);  sc[1]  = fmaf(qv, k0.y, sc[1]);
            sc[2]  = fmaf(qv, k0.z, sc[2]);  sc[3]  = fmaf(qv, k0.w, sc[3]);
            sc[4]  = fmaf(qv, k1.x, sc[4]);  sc[5]  = fmaf(qv, k1.y, sc[5]);
            sc[6]  = fmaf(qv, k1.z, sc[6]);  sc[7]  = fmaf(qv, k1.w, sc[7]);
            sc[8]  = fmaf(qv, k2.x, sc[8]);  sc[9]  = fmaf(qv, k2.y, sc[9]);
            sc[10] = fmaf(qv, k2.z, sc[10]); sc[11] = fmaf(qv, k2.w, sc[11]);
            sc[12] = fmaf(qv, k3.x, sc[12]); sc[13] = fmaf(qv, k3.y, sc[13]);
            sc[14] = fmaf(qv, k3.z, sc[14]); sc[15] = fmaf(qv, k3.w, sc[15]);
        }
        const float scale = 0.03125f;  // C^-0.5 = 1024^-0.5 (full embed dim per reference)
        float mloc = kNegBig;
        #pragma unroll
        for (int j = 0; j < 16; ++j) {
            const int sgl = s0 + (dg << 4) + j;
            float v = sc[j] * scale;
            v = (sgl <= qg) ? v : kNegBig;
            sc[j] = v;
            mloc = fmaxf(mloc, v);
        }
        mloc = fmaxf(mloc, __shfl_xor(mloc, 1));
        mloc = fmaxf(mloc, __shfl_xor(mloc, 2));
        const float mnew = fmaxf(mrun, mloc);
        const float alpha = __expf(mrun - mnew);  // t=0: exp(0)=1 but O=0,lrun=0
        float lsum = 0.f;
        #pragma unroll
        for (int j = 0; j < 16; ++j) {
            const float p = __expf(sc[j] - mnew);  // masked: exp(-1e30-m) = 0
            sc[j] = p;
            lsum += p;
        }
        lsum += __shfl_xor(lsum, 1);
        lsum += __shfl_xor(lsum, 2);
        lrun = lrun * alpha + lsum;
        mrun = mnew;
        #pragma unroll
        for (int i = 0; i < 16; ++i) O[i] *= alpha;
        *(float4*)&Ps[qr][(dg << 4) + 0]  = make_float4(sc[0], sc[1], sc[2], sc[3]);
        *(float4*)&Ps[qr][(dg << 4) + 4]  = make_float4(sc[4], sc[5], sc[6], sc[7]);
        *(float4*)&Ps[qr][(dg << 4) + 8]  = make_float4(sc[8], sc[9], sc[10], sc[11]);
        *(float4*)&Ps[qr][(dg << 4) + 12] = make_float4(sc[12], sc[13], sc[14], sc[15]);
        __syncthreads();

        #pragma unroll
        for (int s = 0; s < 64; ++s) {
            const float p = Ps[qr][s];
            const float4* vp = (const float4*)&Vs[s][dg << 4];
            float4 v0 = vp[0], v1 = vp[1], v2 = vp[2], v3 = vp[3];
            O[0]  = fmaf(p, v0.x, O[0]);  O[1]  = fmaf(p, v0.y, O[1]);
            O[2]  = fmaf(p, v0.z, O[2]);  O[3]  = fmaf(p, v0.w, O[3]);
            O[4]  = fmaf(p, v1.x, O[4]);  O[5]  = fmaf(p, v1.y, O[5]);
            O[6]  = fmaf(p, v1.z, O[6]);  O[7]  = fmaf(p, v1.w, O[7]);
            O[8]  = fmaf(p, v2.x, O[8]);  O[9]  = fmaf(p, v2.y, O[9]);
            O[10] = fmaf(p, v2.z, O[10]); O[11] = fmaf(p, v2.w, O[11]);
            O[12] = fmaf(p, v3.x, O[12]); O[13] = fmaf(p, v3.y, O[13]);
            O[14] = fmaf(p, v3.z, O[14]); O[15] = fmaf(p, v3.w, O[15]);
        }
    }

    const float inv = 1.f / lrun;
    const size_t ob = ((size_t)b * kT + qg) * (size_t)kC + h * 64 + (dg << 4);
    #pragma unroll
    for (int i = 0; i < 4; ++i) {
        float4 ov = make_float4(O[(i << 2) + 0] * inv, O[(i << 2) + 1] * inv,
                                O[(i << 2) + 2] * inv, O[(i << 2) + 3] * inv);
        *(float4*)(Y + ob + (i << 2)) = ov;
    }
}

extern "C" void kernel_launch(void* const* d_in, const int* in_sizes, int n_in,
                              void* d_out, int out_size, void* d_ws, size_t ws_size,
                              hipStream_t stream) {
    const float* x     = (const float*)d_in[0];
    const float* Wq    = (const float*)d_in[1];
    const float* Wk    = (const float*)d_in[2];
    const float* Wv    = (const float*)d_in[3];
    const float* Wproj = (const float*)d_in[4];
    const float* bproj = (const float*)d_in[5];
    const float* W1    = (const float*)d_in[6];
    const float* b1    = (const float*)d_in[7];
    const float* W2    = (const float*)d_in[8];
    const float* b2    = (const float*)d_in[9];

    // Workspace layout with live-range aliasing (f32 elems):
    //   slotA [0, 33.55M): QKV (25.17M, live steps 2-3) | ffh (33.55M, live 5-6)
    //                      attn_y at +25.17M (8.39M, live 3-4)
    //   slotC [33.55M, 41.94M): Wqkv (3.15M, live 1-2) | res1 (8.39M, live 4-6)
    // Peak: 41.94M f32 = 168 MB.
    float* ws     = (float*)d_ws;
    float* QKV    = ws;                                   // [8192,3072]
    float* ffh    = ws;                                   // [8192,4096] (aliases QKV)
    float* attn_y = ws + (size_t)kM * k3C;                // [8192,1024]
    float* Wqkv   = ws + (size_t)kM * kFF;                // [1024,3072]
    float* res1   = Wqkv;                                 // [8192,1024] (aliases Wqkv)
    float* out    = (float*)d_out;

    // 1. pack QKV weights
    repack_qkv<<<(kC * k3C) / 256, 256, 0, stream>>>(Wq, Wk, Wv, Wqkv);
    // 2. QKV = x @ Wqkv                    [8192,1024]x[1024,3072]
    gemm_ep<<<dim3(k3C / 64, kM / 64), 256, 0, stream>>>(
        x, kC, Wqkv, k3C, QKV, k3C, kC, nullptr, nullptr, 0);
    // 3. attention -> attn_y [8192,1024]
    attn_kernel<<<dim3(kT / 64, kB * kH), 256, 0, stream>>>(QKV, attn_y);
    // 4. res1 = attn_y @ Wproj + bproj + x [8192,1024]x[1024,1024]
    gemm_ep<<<dim3(kC / 64, kM / 64), 256, 0, stream>>>(
        attn_y, kC, Wproj, kC, res1, kC, kC, bproj, x, 0);
    // 5. ffh = relu(res1 @ W1 + b1)        [8192,1024]x[1024,4096]
    gemm_ep<<<dim3(kFF / 64, kM / 64), 256, 0, stream>>>(
        res1, kC, W1, kFF, ffh, kFF, kC, b1, nullptr, 1);
    // 6. out = ffh @ W2 + b2 + res1        [8192,4096]x[4096,1024]
    gemm_ep<<<dim3(kC / 64, kM / 64), 256, 0, stream>>>(
        ffh, kFF, W2, kC, out, kC, kFF, b2, res1, 0);
}

// Round 3
// 1684.587 us; speedup vs baseline: 2.4644x; 2.4644x over previous
//
#include <hip/hip_runtime.h>

typedef unsigned short u16;
typedef __attribute__((ext_vector_type(4))) float f32x4;
typedef __attribute__((ext_vector_type(8))) short bf16x8;

constexpr int kB  = 4;
constexpr int kT  = 2048;
constexpr int kC  = 1024;
constexpr int kH  = 16;
constexpr int kFF = 4096;
constexpr int kM  = kB * kT;          // 8192 rows
constexpr int k3C = 3 * kC;           // 3072

__device__ __forceinline__ float b2f(u16 u) {
    union { unsigned int i; float f; } v;
    v.i = ((unsigned int)u) << 16;
    return v.f;
}
__device__ __forceinline__ u16 f2b(float f) {
    union { float f; unsigned int i; } v;
    v.f = f;
    unsigned int r = (v.i + 0x7FFFu + ((v.i >> 16) & 1u)) >> 16;
    return (u16)r;
}

// ---- f32 -> bf16 convert (x) -------------------------------------------------
__global__ void cvt_f32_bf16(const float* __restrict__ in, u16* __restrict__ out, int n4)
{
    const int i = blockIdx.x * 256 + threadIdx.x;
    if (i >= n4) return;
    float4 v = *(const float4*)(in + (size_t)i * 4);
    ushort4 o;
    o.x = f2b(v.x); o.y = f2b(v.y); o.z = f2b(v.z); o.w = f2b(v.w);
    *(ushort4*)(out + (size_t)i * 4) = o;
}

// ---- generic transpose+convert: in f32 [R][Cc] -> out bf16 [Cc][R] ----------
__global__ void transpose_cvt(const float* __restrict__ in, int R, int Cc,
                              u16* __restrict__ out)
{
    __shared__ float t[32][33];
    const int bx = blockIdx.x * 32;  // col base (Cc)
    const int by = blockIdx.y * 32;  // row base (R)
    const int lx = threadIdx.x, ly = threadIdx.y;  // (32, 8)
    #pragma unroll
    for (int i = 0; i < 32; i += 8)
        t[ly + i][lx] = in[(size_t)(by + ly + i) * Cc + bx + lx];
    __syncthreads();
    #pragma unroll
    for (int i = 0; i < 32; i += 8)
        out[(size_t)(bx + ly + i) * R + by + lx] = f2b(t[lx][ly + i]);
}

// ---- QKV weight repack: Wq/Wk/Wv [H,C,64] f32 -> Wqkv_t [3C][C] bf16 --------
// Wqkv_t[s*1024 + h*64 + d][c] = Ws[h][c][d]
__global__ void repack_qkv_t(const float* __restrict__ Wq, const float* __restrict__ Wk,
                             const float* __restrict__ Wv, u16* __restrict__ out)
{
    __shared__ float t[32][33];
    const int z = blockIdx.z;             // 48 = 3 * 16
    const int s = z >> 4, h = z & 15;
    const float* in = (s == 0 ? Wq : s == 1 ? Wk : Wv) + (size_t)h * (kC * 64);
    const int bx = blockIdx.x * 32;       // d base (0/32)
    const int by = blockIdx.y * 32;       // c base
    const int lx = threadIdx.x, ly = threadIdx.y;  // (32, 8)
    #pragma unroll
    for (int i = 0; i < 32; i += 8)
        t[ly + i][lx] = in[(size_t)(by + ly + i) * 64 + bx + lx];
    __syncthreads();
    const int orow = s * kC + h * 64 + bx;
    #pragma unroll
    for (int i = 0; i < 32; i += 8)
        out[(size_t)(orow + ly + i) * kC + by + lx] = f2b(t[lx][ly + i]);
}

// ---- bf16 MFMA GEMM: C[m,n] = A[M,K] @ Bt[N,K]^T (+bias)(relu)(+resid) ------
// 128x128 tile, BK=64, 256 threads = 4 waves (2x2 of 64x64), 4x4 16x16x32 MFMA.
// global_load_lds width-16 staging; XOR k-chunk swizzle for conflict-free ds_read.
__global__ __launch_bounds__(256) void gemm_bt_mfma(
    const u16* __restrict__ A, int lda,
    const u16* __restrict__ Bt, int ldb,
    int K,
    const float* __restrict__ bias,   // f32 [N] or null
    const u16* __restrict__ resid,    // bf16 [M,ldc] or null
    float* __restrict__ CoF,          // f32 out (or null)
    u16* __restrict__ CoB,            // bf16 out (or null)
    int ldc, int do_relu)
{
    constexpr int BK = 64;
    __shared__ u16 As[128 * BK];   // [m][k] row-major (logical k-chunk XOR (m&7))
    __shared__ u16 Bs[128 * BK];   // [n][k] row-major (same swizzle)
    const int tid  = threadIdx.x;
    const int wave = tid >> 6, lane = tid & 63;
    const int wm = (wave >> 1) * 64, wn = (wave & 1) * 64;
    const int m0 = blockIdx.y * 128, n0 = blockIdx.x * 128;

    // staging: wave stages rows [wave*32, +32) of each tile; 4 instr x 8 rows
    const int srow = wave * 32;
    const int lrow = lane >> 3;                      // 0..7 row within group
    const int scol = ((lane & 7) ^ lrow) * 8;        // swizzled k-chunk (elements)

    // fragment addressing
    const int fm   = lane & 15;                      // row/col within 16-tile
    const int fkq  = lane >> 4;                      // k quad 0..3

    f32x4 acc[4][4];
    #pragma unroll
    for (int i = 0; i < 4; ++i)
        #pragma unroll
        for (int j = 0; j < 4; ++j)
            acc[i][j] = (f32x4){0.f, 0.f, 0.f, 0.f};

    for (int k0 = 0; k0 < K; k0 += BK) {
        #pragma unroll
        for (int i = 0; i < 4; ++i) {
            const int r = srow + i * 8;
            const u16* ga = A  + (size_t)(m0 + r + lrow) * lda + k0 + scol;
            const u16* gb = Bt + (size_t)(n0 + r + lrow) * ldb + k0 + scol;
            __builtin_amdgcn_global_load_lds(
                (const __attribute__((address_space(1))) void*)ga,
                (__attribute__((address_space(3))) void*)&As[r * BK], 16, 0, 0);
            __builtin_amdgcn_global_load_lds(
                (const __attribute__((address_space(1))) void*)gb,
                (__attribute__((address_space(3))) void*)&Bs[r * BK], 16, 0, 0);
        }
        __syncthreads();
        #pragma unroll
        for (int ks = 0; ks < 2; ++ks) {
            bf16x8 a[4], b[4];
            #pragma unroll
            for (int i = 0; i < 4; ++i) {
                const int m = wm + i * 16 + fm;
                const int ck = ((ks * 4 + fkq) ^ (m & 7)) * 8;
                a[i] = *(const bf16x8*)&As[m * BK + ck];
            }
            #pragma unroll
            for (int j = 0; j < 4; ++j) {
                const int n = wn + j * 16 + fm;
                const int ck = ((ks * 4 + fkq) ^ (n & 7)) * 8;
                b[j] = *(const bf16x8*)&Bs[n * BK + ck];
            }
            #pragma unroll
            for (int i = 0; i < 4; ++i)
                #pragma unroll
                for (int j = 0; j < 4; ++j)
                    acc[i][j] = __builtin_amdgcn_mfma_f32_16x16x32_bf16(
                        a[i], b[j], acc[i][j], 0, 0, 0);
        }
        __syncthreads();
    }

    // epilogue: C/D layout col = lane&15 (n), row = (lane>>4)*4 + reg (m)
    const int col = lane & 15;
    const int rb  = (lane >> 4) * 4;
    #pragma unroll
    for (int i = 0; i < 4; ++i) {
        #pragma unroll
        for (int j = 0; j < 4; ++j) {
            const int n = n0 + wn + j * 16 + col;
            #pragma unroll
            for (int r = 0; r < 4; ++r) {
                const int m = m0 + wm + i * 16 + rb + r;
                float v = acc[i][j][r];
                if (bias)    v += bias[n];
                if (do_relu) v = fmaxf(v, 0.f);
                if (resid)   v += b2f(resid[(size_t)m * ldc + n]);
                if (CoF) CoF[(size_t)m * ldc + n] = v;
                else     CoB[(size_t)m * ldc + n] = f2b(v);
            }
        }
    }
}

// ---- Flash-style causal attention (bf16 i/o, f32 compute) -------------------
__global__ __launch_bounds__(256) void attn_kernel(
    const u16* __restrict__ QKV, u16* __restrict__ Y)
{
    __shared__ float Kst[64][68];  // transposed: [d][s]
    __shared__ float Vs[64][68];   // [s][d]
    __shared__ float Ps[64][68];   // [q][s]
    const int tid = threadIdx.x;
    const int qt = blockIdx.x, bh = blockIdx.y;
    const int b = bh >> 4, h = bh & 15;
    const int q0 = qt << 6;
    const int qr = tid >> 2, dg = tid & 3;
    const int qg = q0 + qr;
    const float kNegBig = -1e30f;
    const size_t qrow = ((size_t)b * kT + qg) * (size_t)k3C + h * 64;

    float qreg[64];
    #pragma unroll
    for (int i = 0; i < 16; ++i) {
        ushort4 u = *(const ushort4*)(QKV + qrow + (i << 2));
        qreg[(i << 2) + 0] = b2f(u.x); qreg[(i << 2) + 1] = b2f(u.y);
        qreg[(i << 2) + 2] = b2f(u.z); qreg[(i << 2) + 3] = b2f(u.w);
    }
    float O[16];
    #pragma unroll
    for (int i = 0; i < 16; ++i) O[i] = 0.f;
    float mrun = kNegBig, lrun = 0.f;
    const int ntiles = qt + 1;

    for (int t = 0; t < ntiles; ++t) {
        const int s0 = t << 6;
        __syncthreads();
        {
            const size_t kb = ((size_t)b * kT + s0 + qr) * (size_t)k3C + kC + h * 64 + (dg << 4);
            #pragma unroll
            for (int i = 0; i < 4; ++i) {
                ushort4 u = *(const ushort4*)(QKV + kb + (i << 2));
                const int dd = (dg << 4) + (i << 2);
                Kst[dd + 0][qr] = b2f(u.x);
                Kst[dd + 1][qr] = b2f(u.y);
                Kst[dd + 2][qr] = b2f(u.z);
                Kst[dd + 3][qr] = b2f(u.w);
                ushort4 w = *(const ushort4*)(QKV + kb + kC + (i << 2));
                *(float4*)&Vs[qr][dd] = make_float4(b2f(w.x), b2f(w.y), b2f(w.z), b2f(w.w));
            }
        }
        __syncthreads();

        float sc[16];
        #pragma unroll
        for (int j = 0; j < 16; ++j) sc[j] = 0.f;
        #pragma unroll
        for (int d = 0; d < 64; ++d) {
            const float qv = qreg[d];
            const float4* kp = (const float4*)&Kst[d][dg << 4];
            float4 k0 = kp[0], k1 = kp[1], k2 = kp[2], k3 = kp[3];
            sc[0]  = fmaf(qv, k0.x, sc[0]);  sc[1]  = fmaf(qv, k0.y, sc[1]);
            sc[2]  = fmaf(qv, k0.z, sc[2]);  sc[3]  = fmaf(qv, k0.w, sc[3]);
            sc[4]  = fmaf(qv, k1.x, sc[4]);  sc[5]  = fmaf(qv, k1.y, sc[5]);
            sc[6]  = fmaf(qv, k1.z, sc[6]);  sc[7]  = fmaf(qv, k1.w, sc[7]);
            sc[8]  = fmaf(qv, k2.x, sc[8]);  sc[9]  = fmaf(qv, k2.y, sc[9]);
            sc[10] = fmaf(qv, k2.z, sc[10]); sc[11] = fmaf(qv, k2.w, sc[11]);
            sc[12] = fmaf(qv, k3.x, sc[12]); sc[13] = fmaf(qv, k3.y, sc[13]);
            sc[14] = fmaf(qv, k3.z, sc[14]); sc[15] = fmaf(qv, k3.w, sc[15]);
        }
        const float scale = 0.03125f;  // 1024^-0.5 (full embed dim per reference)
        float mloc = kNegBig;
        #pragma unroll
        for (int j = 0; j < 16; ++j) {
            const int sgl = s0 + (dg << 4) + j;
            float v = sc[j] * scale;
            v = (sgl <= qg) ? v : kNegBig;
            sc[j] = v;
            mloc = fmaxf(mloc, v);
        }
        mloc = fmaxf(mloc, __shfl_xor(mloc, 1));
        mloc = fmaxf(mloc, __shfl_xor(mloc, 2));
        const float mnew = fmaxf(mrun, mloc);
        const float alpha = __expf(mrun - mnew);
        float lsum = 0.f;
        #pragma unroll
        for (int j = 0; j < 16; ++j) {
            const float p = __expf(sc[j] - mnew);
            sc[j] = p;
            lsum += p;
        }
        lsum += __shfl_xor(lsum, 1);
        lsum += __shfl_xor(lsum, 2);
        lrun = lrun * alpha + lsum;
        mrun = mnew;
        #pragma unroll
        for (int i = 0; i < 16; ++i) O[i] *= alpha;
        *(float4*)&Ps[qr][(dg << 4) + 0]  = make_float4(sc[0], sc[1], sc[2], sc[3]);
        *(float4*)&Ps[qr][(dg << 4) + 4]  = make_float4(sc[4], sc[5], sc[6], sc[7]);
        *(float4*)&Ps[qr][(dg << 4) + 8]  = make_float4(sc[8], sc[9], sc[10], sc[11]);
        *(float4*)&Ps[qr][(dg << 4) + 12] = make_float4(sc[12], sc[13], sc[14], sc[15]);
        __syncthreads();

        #pragma unroll
        for (int s = 0; s < 64; ++s) {
            const float p = Ps[qr][s];
            const float4* vp = (const float4*)&Vs[s][dg << 4];
            float4 v0 = vp[0], v1 = vp[1], v2 = vp[2], v3 = vp[3];
            O[0]  = fmaf(p, v0.x, O[0]);  O[1]  = fmaf(p, v0.y, O[1]);
            O[2]  = fmaf(p, v0.z, O[2]);  O[3]  = fmaf(p, v0.w, O[3]);
            O[4]  = fmaf(p, v1.x, O[4]);  O[5]  = fmaf(p, v1.y, O[5]);
            O[6]  = fmaf(p, v1.z, O[6]);  O[7]  = fmaf(p, v1.w, O[7]);
            O[8]  = fmaf(p, v2.x, O[8]);  O[9]  = fmaf(p, v2.y, O[9]);
            O[10] = fmaf(p, v2.z, O[10]); O[11] = fmaf(p, v2.w, O[11]);
            O[12] = fmaf(p, v3.x, O[12]); O[13] = fmaf(p, v3.y, O[13]);
            O[14] = fmaf(p, v3.z, O[14]); O[15] = fmaf(p, v3.w, O[15]);
        }
    }

    const float inv = 1.f / lrun;
    const size_t ob = ((size_t)b * kT + qg) * (size_t)kC + h * 64 + (dg << 4);
    #pragma unroll
    for (int i = 0; i < 4; ++i) {
        ushort4 ov;
        ov.x = f2b(O[(i << 2) + 0] * inv);
        ov.y = f2b(O[(i << 2) + 1] * inv);
        ov.z = f2b(O[(i << 2) + 2] * inv);
        ov.w = f2b(O[(i << 2) + 3] * inv);
        *(ushort4*)(Y + ob + (i << 2)) = ov;
    }
}

extern "C" void kernel_launch(void* const* d_in, const int* in_sizes, int n_in,
                              void* d_out, int out_size, void* d_ws, size_t ws_size,
                              hipStream_t stream) {
    const float* x     = (const float*)d_in[0];
    const float* Wq    = (const float*)d_in[1];
    const float* Wk    = (const float*)d_in[2];
    const float* Wv    = (const float*)d_in[3];
    const float* Wproj = (const float*)d_in[4];
    const float* bproj = (const float*)d_in[5];
    const float* W1    = (const float*)d_in[6];
    const float* b1    = (const float*)d_in[7];
    const float* W2    = (const float*)d_in[8];
    const float* b2    = (const float*)d_in[9];

    // Workspace (bf16 elements). QKV (live 2-3) aliases ffh (live 5-6).
    // Total 71.3M elems = 143 MB.
    u16* ws      = (u16*)d_ws;
    u16* QKV     = ws;                                  // [8192,3072]
    u16* ffh     = ws;                                  // [8192,4096]
    u16* attn_y  = ws + (size_t)kM * kFF;               // [8192,1024]
    u16* xb      = attn_y  + (size_t)kM * kC;           // [8192,1024]
    u16* res1    = xb      + (size_t)kM * kC;           // [8192,1024]
    u16* Wqkv_t  = res1    + (size_t)kM * kC;           // [3072,1024]
    u16* Wproj_t = Wqkv_t  + (size_t)k3C * kC;          // [1024,1024]
    u16* W1t     = Wproj_t + (size_t)kC * kC;           // [4096,1024]
    u16* W2t     = W1t     + (size_t)kFF * kC;          // [1024,4096]
    float* out   = (float*)d_out;

    // 0. converts / repacks
    cvt_f32_bf16<<<(kM * kC / 4 + 255) / 256, 256, 0, stream>>>(x, xb, kM * kC / 4);
    repack_qkv_t<<<dim3(2, kC / 32, 48), dim3(32, 8), 0, stream>>>(Wq, Wk, Wv, Wqkv_t);
    transpose_cvt<<<dim3(kC / 32, kC / 32),  dim3(32, 8), 0, stream>>>(Wproj, kC, kC, Wproj_t);
    transpose_cvt<<<dim3(kFF / 32, kC / 32), dim3(32, 8), 0, stream>>>(W1, kC, kFF, W1t);
    transpose_cvt<<<dim3(kC / 32, kFF / 32), dim3(32, 8), 0, stream>>>(W2, kFF, kC, W2t);

    // 1. QKV = xb @ Wqkv_t^T            [8192,1024] x [3072,1024]^T -> bf16
    gemm_bt_mfma<<<dim3(k3C / 128, kM / 128), 256, 0, stream>>>(
        xb, kC, Wqkv_t, kC, kC, nullptr, nullptr, nullptr, QKV, k3C, 0);
    // 2. attention -> attn_y bf16
    attn_kernel<<<dim3(kT / 64, kB * kH), 256, 0, stream>>>(QKV, attn_y);
    // 3. res1 = attn_y @ Wproj + bproj + xb -> bf16
    gemm_bt_mfma<<<dim3(kC / 128, kM / 128), 256, 0, stream>>>(
        attn_y, kC, Wproj_t, kC, kC, bproj, xb, nullptr, res1, kC, 0);
    // 4. ffh = relu(res1 @ W1 + b1) -> bf16
    gemm_bt_mfma<<<dim3(kFF / 128, kM / 128), 256, 0, stream>>>(
        res1, kC, W1t, kC, kC, b1, nullptr, nullptr, ffh, kFF, 1);
    // 5. out = ffh @ W2 + b2 + res1 -> f32 (d_out)
    gemm_bt_mfma<<<dim3(kC / 128, kM / 128), 256, 0, stream>>>(
        ffh, kFF, W2t, kFF, kFF, b2, res1, out, nullptr, kC, 0);
}

// Round 4
// 736.005 us; speedup vs baseline: 5.6406x; 2.2888x over previous
//
#include <hip/hip_runtime.h>

typedef unsigned short u16;
typedef __attribute__((ext_vector_type(4))) float f32x4;
typedef __attribute__((ext_vector_type(8))) short bf16x8;

constexpr int kB  = 4;
constexpr int kT  = 2048;
constexpr int kC  = 1024;
constexpr int kH  = 16;
constexpr int kFF = 4096;
constexpr int kM  = kB * kT;          // 8192 rows
constexpr int k3C = 3 * kC;           // 3072

__device__ __forceinline__ float b2f(u16 u) {
    union { unsigned int i; float f; } v;
    v.i = ((unsigned int)u) << 16;
    return v.f;
}
__device__ __forceinline__ u16 f2b(float f) {
    union { float f; unsigned int i; } v;
    v.f = f;
    unsigned int r = (v.i + 0x7FFFu + ((v.i >> 16) & 1u)) >> 16;
    return (u16)r;
}

// ---- f32 -> bf16 convert (x) -------------------------------------------------
__global__ void cvt_f32_bf16(const float* __restrict__ in, u16* __restrict__ out, int n4)
{
    const int i = blockIdx.x * 256 + threadIdx.x;
    if (i >= n4) return;
    float4 v = *(const float4*)(in + (size_t)i * 4);
    ushort4 o;
    o.x = f2b(v.x); o.y = f2b(v.y); o.z = f2b(v.z); o.w = f2b(v.w);
    *(ushort4*)(out + (size_t)i * 4) = o;
}

// ---- generic transpose+convert: in f32 [R][Cc] -> out bf16 [Cc][R] ----------
__global__ void transpose_cvt(const float* __restrict__ in, int R, int Cc,
                              u16* __restrict__ out)
{
    __shared__ float t[32][33];
    const int bx = blockIdx.x * 32;  // col base (Cc)
    const int by = blockIdx.y * 32;  // row base (R)
    const int lx = threadIdx.x, ly = threadIdx.y;  // (32, 8)
    #pragma unroll
    for (int i = 0; i < 32; i += 8)
        t[ly + i][lx] = in[(size_t)(by + ly + i) * Cc + bx + lx];
    __syncthreads();
    #pragma unroll
    for (int i = 0; i < 32; i += 8)
        out[(size_t)(bx + ly + i) * R + by + lx] = f2b(t[lx][ly + i]);
}

// ---- QKV weight repack: Wq/Wk/Wv [H,C,64] f32 -> Wqkv_t [3C][C] bf16 --------
__global__ void repack_qkv_t(const float* __restrict__ Wq, const float* __restrict__ Wk,
                             const float* __restrict__ Wv, u16* __restrict__ out)
{
    __shared__ float t[32][33];
    const int z = blockIdx.z;             // 48 = 3 * 16
    const int s = z >> 4, h = z & 15;
    const float* in = (s == 0 ? Wq : s == 1 ? Wk : Wv) + (size_t)h * (kC * 64);
    const int bx = blockIdx.x * 32;       // d base (0/32)
    const int by = blockIdx.y * 32;       // c base
    const int lx = threadIdx.x, ly = threadIdx.y;  // (32, 8)
    #pragma unroll
    for (int i = 0; i < 32; i += 8)
        t[ly + i][lx] = in[(size_t)(by + ly + i) * 64 + bx + lx];
    __syncthreads();
    const int orow = s * kC + h * 64 + bx;
    #pragma unroll
    for (int i = 0; i < 32; i += 8)
        out[(size_t)(orow + ly + i) * kC + by + lx] = f2b(t[lx][ly + i]);
}

// ---- bf16 MFMA GEMM: C[m,n] = A[M,K] @ Bt[N,K]^T (+bias)(relu)(+resid) ------
__global__ __launch_bounds__(256) void gemm_bt_mfma(
    const u16* __restrict__ A, int lda,
    const u16* __restrict__ Bt, int ldb,
    int K,
    const float* __restrict__ bias,
    const u16* __restrict__ resid,
    float* __restrict__ CoF,
    u16* __restrict__ CoB,
    int ldc, int do_relu)
{
    constexpr int BK = 64;
    __shared__ u16 As[128 * BK];
    __shared__ u16 Bs[128 * BK];
    const int tid  = threadIdx.x;
    const int wave = tid >> 6, lane = tid & 63;
    const int wm = (wave >> 1) * 64, wn = (wave & 1) * 64;
    const int m0 = blockIdx.y * 128, n0 = blockIdx.x * 128;

    const int srow = wave * 32;
    const int lrow = lane >> 3;
    const int scol = ((lane & 7) ^ lrow) * 8;

    const int fm   = lane & 15;
    const int fkq  = lane >> 4;

    f32x4 acc[4][4];
    #pragma unroll
    for (int i = 0; i < 4; ++i)
        #pragma unroll
        for (int j = 0; j < 4; ++j)
            acc[i][j] = (f32x4){0.f, 0.f, 0.f, 0.f};

    for (int k0 = 0; k0 < K; k0 += BK) {
        #pragma unroll
        for (int i = 0; i < 4; ++i) {
            const int r = srow + i * 8;
            const u16* ga = A  + (size_t)(m0 + r + lrow) * lda + k0 + scol;
            const u16* gb = Bt + (size_t)(n0 + r + lrow) * ldb + k0 + scol;
            __builtin_amdgcn_global_load_lds(
                (const __attribute__((address_space(1))) void*)ga,
                (__attribute__((address_space(3))) void*)&As[r * BK], 16, 0, 0);
            __builtin_amdgcn_global_load_lds(
                (const __attribute__((address_space(1))) void*)gb,
                (__attribute__((address_space(3))) void*)&Bs[r * BK], 16, 0, 0);
        }
        __syncthreads();
        #pragma unroll
        for (int ks = 0; ks < 2; ++ks) {
            bf16x8 a[4], b[4];
            #pragma unroll
            for (int i = 0; i < 4; ++i) {
                const int m = wm + i * 16 + fm;
                const int ck = ((ks * 4 + fkq) ^ (m & 7)) * 8;
                a[i] = *(const bf16x8*)&As[m * BK + ck];
            }
            #pragma unroll
            for (int j = 0; j < 4; ++j) {
                const int n = wn + j * 16 + fm;
                const int ck = ((ks * 4 + fkq) ^ (n & 7)) * 8;
                b[j] = *(const bf16x8*)&Bs[n * BK + ck];
            }
            #pragma unroll
            for (int i = 0; i < 4; ++i)
                #pragma unroll
                for (int j = 0; j < 4; ++j)
                    acc[i][j] = __builtin_amdgcn_mfma_f32_16x16x32_bf16(
                        a[i], b[j], acc[i][j], 0, 0, 0);
        }
        __syncthreads();
    }

    const int col = lane & 15;
    const int rb  = (lane >> 4) * 4;
    #pragma unroll
    for (int i = 0; i < 4; ++i) {
        #pragma unroll
        for (int j = 0; j < 4; ++j) {
            const int n = n0 + wn + j * 16 + col;
            #pragma unroll
            for (int r = 0; r < 4; ++r) {
                const int m = m0 + wm + i * 16 + rb + r;
                float v = acc[i][j][r];
                if (bias)    v += bias[n];
                if (do_relu) v = fmaxf(v, 0.f);
                if (resid)   v += b2f(resid[(size_t)m * ldc + n]);
                if (CoF) CoF[(size_t)m * ldc + n] = v;
                else     CoB[(size_t)m * ldc + n] = f2b(v);
            }
        }
    }
}

// ---- MFMA flash attention ---------------------------------------------------
// Block = 4 waves; wave w owns q rows [q0+16w, +16). K-tiles of 64.
// QK^T and PV via mfma_f32_16x16x32_bf16; P converts C/D->A layout through LDS.
// All LDS arrays use XOR-chunk swizzle (one address function for read+write).
__global__ __launch_bounds__(256) void attn_mfma(
    const u16* __restrict__ QKV, u16* __restrict__ Y)
{
    __shared__ __align__(16) u16 Kl[64 * 64];        // K-tile [s][d], swizzled
    __shared__ __align__(16) u16 Vt[64 * 64];        // V-tile transposed [d][s], swizzled
    __shared__ __align__(16) u16 Pl[4 * 16 * 64];    // per-wave P [q][s], swizzled

    const int tid  = threadIdx.x;
    const int wave = tid >> 6, lane = tid & 63;
    const int ln   = lane & 15, quad = lane >> 4;
    const int qt = blockIdx.x, bh = blockIdx.y;
    const int b = bh >> 4, h = bh & 15;
    const int q0 = qt << 6;
    const int bT = b * kT;
    const int qgb = q0 + wave * 16 + quad * 4;       // this lane's q-row base (+r)
    const float scale = 0.03125f;                    // 1024^-0.5 (full embed dim)

    // Q fragments (A-operand): lane holds Q[m=ln][k=quad*8+j (+32*ks)]
    bf16x8 qa[2];
    {
        const size_t qb = ((size_t)bT + q0 + wave * 16 + ln) * k3C + h * 64;
        qa[0] = *(const bf16x8*)(QKV + qb + quad * 8);
        qa[1] = *(const bf16x8*)(QKV + qb + 32 + quad * 8);
    }

    f32x4 acco[4];
    #pragma unroll
    for (int j = 0; j < 4; ++j) acco[j] = (f32x4){0.f, 0.f, 0.f, 0.f};
    float mrun[4], lrun[4];
    #pragma unroll
    for (int r = 0; r < 4; ++r) { mrun[r] = -1e30f; lrun[r] = 0.f; }

    const int pbase = wave * (16 * 64);

    for (int t = 0; t <= qt; ++t) {
        const int s0 = t << 6;
        // -- cooperative K/V tile load --
        #pragma unroll
        for (int p = 0; p < 2; ++p) {
            const int id = tid + p * 256;            // 0..511 chunk id
            const int s = id >> 3, c = id & 7;
            const u16* g = QKV + ((size_t)bT + s0 + s) * k3C + kC + h * 64 + c * 8;
            uint4 v = *(const uint4*)g;
            *(uint4*)&Kl[(s << 6) + (((c ^ (s & 7)) << 3))] = v;
        }
        {
            const int s = tid >> 2, d0 = (tid & 3) << 4;
            const u16* g = QKV + ((size_t)bT + s0 + s) * k3C + 2 * kC + h * 64 + d0;
            uint4 va = *(const uint4*)g;
            uint4 vb = *(const uint4*)(g + 8);
            u16 tmp[16];
            *(uint4*)&tmp[0] = va;
            *(uint4*)&tmp[8] = vb;
            #pragma unroll
            for (int i = 0; i < 16; ++i) {
                const int d = d0 + i;
                Vt[(d << 6) + (((((s >> 3) ^ (d & 7) ^ ((d >> 4) & 3)) << 3) + (s & 7)))] = tmp[i];
            }
        }
        __syncthreads();

        // -- QK^T: S[16q x 64s] in 4 C/D tiles --
        f32x4 accs[4];
        #pragma unroll
        for (int j = 0; j < 4; ++j) accs[j] = (f32x4){0.f, 0.f, 0.f, 0.f};
        #pragma unroll
        for (int ks = 0; ks < 2; ++ks) {
            #pragma unroll
            for (int j = 0; j < 4; ++j) {
                const int s = j * 16 + ln;
                bf16x8 kb = *(const bf16x8*)&Kl[(s << 6) + (((quad + 4 * ks) ^ (s & 7)) << 3)];
                accs[j] = __builtin_amdgcn_mfma_f32_16x16x32_bf16(qa[ks], kb, accs[j], 0, 0, 0);
            }
        }

        // -- mask + scale --
        #pragma unroll
        for (int j = 0; j < 4; ++j) {
            const int sg = s0 + j * 16 + ln;
            #pragma unroll
            for (int r = 0; r < 4; ++r) {
                const float v = accs[j][r] * scale;
                accs[j][r] = (sg <= qgb + r) ? v : -1e30f;
            }
        }
        // -- online softmax per q-row r --
        #pragma unroll
        for (int r = 0; r < 4; ++r) {
            float mx = fmaxf(fmaxf(accs[0][r], accs[1][r]), fmaxf(accs[2][r], accs[3][r]));
            mx = fmaxf(mx, __shfl_xor(mx, 1));
            mx = fmaxf(mx, __shfl_xor(mx, 2));
            mx = fmaxf(mx, __shfl_xor(mx, 4));
            mx = fmaxf(mx, __shfl_xor(mx, 8));
            const float mn = fmaxf(mrun[r], mx);
            const float al = __expf(mrun[r] - mn);
            float ls = 0.f;
            #pragma unroll
            for (int j = 0; j < 4; ++j) {
                const float p = __expf(accs[j][r] - mn);
                accs[j][r] = p;
                ls += p;
            }
            ls += __shfl_xor(ls, 1);
            ls += __shfl_xor(ls, 2);
            ls += __shfl_xor(ls, 4);
            ls += __shfl_xor(ls, 8);
            lrun[r] = lrun[r] * al + ls;
            mrun[r] = mn;
            #pragma unroll
            for (int j = 0; j < 4; ++j) acco[j][r] *= al;
        }

        // -- write P (C/D layout -> LDS [q][s]) --
        #pragma unroll
        for (int j = 0; j < 4; ++j) {
            const int s = j * 16 + ln;
            #pragma unroll
            for (int r = 0; r < 4; ++r) {
                const int ql = quad * 4 + r;
                Pl[pbase + (ql << 6) + ((((s >> 3) ^ (ql & 7)) << 3) + (s & 7))] = f2b(accs[j][r]);
            }
        }
        // (same-wave LDS write->read ordering handled by lgkmcnt)

        // -- PV: O += P[16q x 64s] @ V[64s x 64d] --
        bf16x8 pa[2];
        #pragma unroll
        for (int ks = 0; ks < 2; ++ks)
            pa[ks] = *(const bf16x8*)&Pl[pbase + (ln << 6) + (((quad + 4 * ks) ^ (ln & 7)) << 3)];
        #pragma unroll
        for (int jd = 0; jd < 4; ++jd) {
            const int d = jd * 16 + ln;
            #pragma unroll
            for (int ks = 0; ks < 2; ++ks) {
                bf16x8 vb = *(const bf16x8*)&Vt[(d << 6) + ((((quad + 4 * ks) ^ (d & 7) ^ jd) << 3))];
                acco[jd] = __builtin_amdgcn_mfma_f32_16x16x32_bf16(pa[ks], vb, acco[jd], 0, 0, 0);
            }
        }
        __syncthreads();
    }

    // -- epilogue: normalize, write Y [B*T, C] --
    float inv[4];
    #pragma unroll
    for (int r = 0; r < 4; ++r) inv[r] = 1.f / lrun[r];
    #pragma unroll
    for (int jd = 0; jd < 4; ++jd) {
        const int col = h * 64 + jd * 16 + ln;
        #pragma unroll
        for (int r = 0; r < 4; ++r) {
            const int qg = qgb + r;
            Y[((size_t)bT + qg) * kC + col] = f2b(acco[jd][r] * inv[r]);
        }
    }
}

extern "C" void kernel_launch(void* const* d_in, const int* in_sizes, int n_in,
                              void* d_out, int out_size, void* d_ws, size_t ws_size,
                              hipStream_t stream) {
    const float* x     = (const float*)d_in[0];
    const float* Wq    = (const float*)d_in[1];
    const float* Wk    = (const float*)d_in[2];
    const float* Wv    = (const float*)d_in[3];
    const float* Wproj = (const float*)d_in[4];
    const float* bproj = (const float*)d_in[5];
    const float* W1    = (const float*)d_in[6];
    const float* b1    = (const float*)d_in[7];
    const float* W2    = (const float*)d_in[8];
    const float* b2    = (const float*)d_in[9];

    // Workspace (bf16 elements). QKV (live 2-3) aliases ffh (live 5-6).
    u16* ws      = (u16*)d_ws;
    u16* QKV     = ws;                                  // [8192,3072]
    u16* ffh     = ws;                                  // [8192,4096]
    u16* attn_y  = ws + (size_t)kM * kFF;               // [8192,1024]
    u16* xb      = attn_y  + (size_t)kM * kC;           // [8192,1024]
    u16* res1    = xb      + (size_t)kM * kC;           // [8192,1024]
    u16* Wqkv_t  = res1    + (size_t)kM * kC;           // [3072,1024]
    u16* Wproj_t = Wqkv_t  + (size_t)k3C * kC;          // [1024,1024]
    u16* W1t     = Wproj_t + (size_t)kC * kC;           // [4096,1024]
    u16* W2t     = W1t     + (size_t)kFF * kC;          // [1024,4096]
    float* out   = (float*)d_out;

    // 0. converts / repacks
    cvt_f32_bf16<<<(kM * kC / 4 + 255) / 256, 256, 0, stream>>>(x, xb, kM * kC / 4);
    repack_qkv_t<<<dim3(2, kC / 32, 48), dim3(32, 8), 0, stream>>>(Wq, Wk, Wv, Wqkv_t);
    transpose_cvt<<<dim3(kC / 32, kC / 32),  dim3(32, 8), 0, stream>>>(Wproj, kC, kC, Wproj_t);
    transpose_cvt<<<dim3(kFF / 32, kC / 32), dim3(32, 8), 0, stream>>>(W1, kC, kFF, W1t);
    transpose_cvt<<<dim3(kC / 32, kFF / 32), dim3(32, 8), 0, stream>>>(W2, kFF, kC, W2t);

    // 1. QKV = xb @ Wqkv_t^T
    gemm_bt_mfma<<<dim3(k3C / 128, kM / 128), 256, 0, stream>>>(
        xb, kC, Wqkv_t, kC, kC, nullptr, nullptr, nullptr, QKV, k3C, 0);
    // 2. attention -> attn_y bf16
    attn_mfma<<<dim3(kT / 64, kB * kH), 256, 0, stream>>>(QKV, attn_y);
    // 3. res1 = attn_y @ Wproj + bproj + xb
    gemm_bt_mfma<<<dim3(kC / 128, kM / 128), 256, 0, stream>>>(
        attn_y, kC, Wproj_t, kC, kC, bproj, xb, nullptr, res1, kC, 0);
    // 4. ffh = relu(res1 @ W1 + b1)
    gemm_bt_mfma<<<dim3(kFF / 128, kM / 128), 256, 0, stream>>>(
        res1, kC, W1t, kC, kC, b1, nullptr, nullptr, ffh, kFF, 1);
    // 5. out = ffh @ W2 + b2 + res1 -> f32 (d_out)
    gemm_bt_mfma<<<dim3(kC / 128, kM / 128), 256, 0, stream>>>(
        ffh, kFF, W2t, kFF, kFF, b2, res1, out, nullptr, kC, 0);
}